// Round 8
// baseline (515.741 us; speedup 1.0000x reference)
//
#include <hip/hip_runtime.h>
#include <stdint.h>

#define D_    10000
#define DP1   10001
#define NPAD2 10240      // 40 * 256 (padded vocab rows for GEMM1, N-tile 256)
#define H_    1024
#define BL    4096       // B * L
#define CANDS 1024       // candidate list capacity (p > 1e-7 of mass; typ. 2-6)

typedef float  f32x4  __attribute__((ext_vector_type(4)));
typedef __bf16 bf16x8 __attribute__((ext_vector_type(8)));
typedef unsigned short u16;
typedef u16    u16x8  __attribute__((ext_vector_type(8)));

// ---------- bf16 helpers (round-to-nearest-even) ----------
__device__ __forceinline__ u16 f2bf(float x) {
    union { float f; unsigned u; } v; v.f = x;
    unsigned r = v.u + 0x7FFFu + ((v.u >> 16) & 1u);
    return (u16)(r >> 16);
}
__device__ __forceinline__ float bf2f(u16 b) {
    union { float f; unsigned u; } v; v.u = ((unsigned)b) << 16;
    return v.f;
}

// async global -> LDS, 16B per lane (HW: wave-uniform base + lane*16)
#define GLOAD_LDS16(gsrc, ldst)                                             \
    __builtin_amdgcn_global_load_lds(                                       \
        (__attribute__((address_space(1))) void*)(void*)(gsrc),             \
        (__attribute__((address_space(3))) void*)(void*)(ldst), 16, 0, 0)

// History:
// R3: LDS chunk swizzle -> SQ_LDS_BANK_CONFLICT 2.07e7 -> 0.
// R6: 2-deep prefetch + counted vmcnt, (512,2), 96KB: 248-252us (PROVEN).
// R7: 256^2 tile + 4-phase: REGRESSED. Reverted.
// R8: sparse-gather epilogue replaced gemm2 pipeline: 692->648us.
// R9/R10: spill disasters. LESSON: WRITE_SIZE >> output = scratch spill.
// R11: consolidation: 517us. R12: vectorized splits + 1024t softmax:
//   512us (-5 only) -> FALSIFIED "splits slow/occupancy" theory. Pinned:
//   softmax_gather ~235us vs 57us traffic floor (~1.5TB/s effective).
// R13 (this): HYPOTHESIS: sim rows misaligned (10001 % 4 == 1 -> 3/4 of
//   rows have base % 16B != 0) => every f32x4 ld/st in softmax_gather is a
//   misaligned 128-bit op (slow path). Fix: per-row head fix-up a0 =
//   (4-(row&3))&3 scalar elems, then all vector ops 16B-aligned. Only
//   softmax_gather touches sim with vector ops. Predict 235 -> ~80us.

// ---------- prep: split fp32 -> bf16 hi + lo (8 elements/thread) ----------
__global__ __launch_bounds__(256)
void split_desc_k(const float* __restrict__ desc, u16* __restrict__ hi, u16* __restrict__ lo) {
    size_t i = ((size_t)blockIdx.x * 256 + threadIdx.x) * 8;   // exactly BL*H_
    f32x4 x0 = *(const f32x4*)(desc + i);
    f32x4 x1 = *(const f32x4*)(desc + i + 4);
    u16x8 h, l;
#pragma unroll
    for (int e = 0; e < 4; e++) {
        h[e] = f2bf(x0[e]); l[e] = f2bf(x0[e] - bf2f(h[e]));
        h[4 + e] = f2bf(x1[e]); l[4 + e] = f2bf(x1[e] - bf2f(h[4 + e]));
    }
    *(u16x8*)(hi + i) = h;
    *(u16x8*)(lo + i) = l;
}

__global__ __launch_bounds__(256)
void split_fv_k(const float* __restrict__ vocab, const float* __restrict__ defe,
                u16* __restrict__ hi, u16* __restrict__ lo) {
    size_t i = ((size_t)blockIdx.x * 256 + threadIdx.x) * 8;   // exactly NPAD2*H_
    int d = (int)(i >> 10);                                    // 8-chunk never crosses rows
    f32x4 x0 = {0.f, 0.f, 0.f, 0.f}, x1 = {0.f, 0.f, 0.f, 0.f};
    if (d < D_) {
        x0 = *(const f32x4*)(vocab + i);
        x1 = *(const f32x4*)(vocab + i + 4);
    } else if (d == D_) {
        int h = (int)(i & 1023);
        x0 = *(const f32x4*)(defe + h);
        x1 = *(const f32x4*)(defe + h + 4);
    }
    u16x8 h8, l8;
#pragma unroll
    for (int e = 0; e < 4; e++) {
        h8[e] = f2bf(x0[e]); l8[e] = f2bf(x0[e] - bf2f(h8[e]));
        h8[4 + e] = f2bf(x1[e]); l8[4 + e] = f2bf(x1[e] - bf2f(h8[4 + e]));
    }
    *(u16x8*)(hi + i) = h8;
    *(u16x8*)(lo + i) = l8;
}

// ---------- GEMM1: logits = desc @ full_vocab^T, bf16 hi/lo split (3 MFMAs) ----------
// Tile 128(M) x 256(N), BK=32, 512 threads (8 waves, wave grid 2x4, 64x64/wave).
// Double-buffered LDS (96 KB), 2-deep prefetch with counted vmcnt.  [R6 form]

#define G1_MFMA(a, b, c) __builtin_amdgcn_mfma_f32_16x16x32_bf16((a), (b), (c), 0, 0, 0)

#define G1_STAGE(AhB, AlB, BhB, BlB, kk) do {                               \
    GLOAD_LDS16(a_h  + (kk), (char*)(AhB) + tid16);                         \
    GLOAD_LDS16(a_l  + (kk), (char*)(AlB) + tid16);                         \
    GLOAD_LDS16(b_h0 + (kk), (char*)(BhB) + tid16);                         \
    GLOAD_LDS16(b_h1 + (kk), (char*)(BhB) + tid16 + 8192);                  \
    GLOAD_LDS16(b_l0 + (kk), (char*)(BlB) + tid16);                         \
    GLOAD_LDS16(b_l1 + (kk), (char*)(BlB) + tid16 + 8192);                  \
} while (0)

// One K-tile: phase 0 = {ds_read 16 frags, 24 MFMA (i=0,1), lgkmcnt(0), barrier}
//             phase 1 = {STAGE t+2 -> this buffer, 24 MFMA (i=2,3), vmcnt(6), barrier}
// vmcnt(6): tile t+1's 6 loads (oldest) complete; tile t+2's 6 stay in flight.
#define G1_ITER(AhB, AlB, BhB, BlB, t) do {                                 \
    bf16x8 afh[4], afl[4], bfh[4], bfl[4];                                  \
    _Pragma("unroll")                                                       \
    for (int i = 0; i < 4; i++) {                                           \
        afh[i] = *(const bf16x8*)&AhB[aoff[i]];                             \
        afl[i] = *(const bf16x8*)&AlB[aoff[i]];                             \
        bfh[i] = *(const bf16x8*)&BhB[boff[i]];                             \
        bfl[i] = *(const bf16x8*)&BlB[boff[i]];                             \
    }                                                                       \
    __builtin_amdgcn_s_setprio(1);                                          \
    _Pragma("unroll")                                                       \
    for (int i = 0; i < 2; i++)                                             \
        _Pragma("unroll")                                                   \
        for (int j = 0; j < 4; j++) {                                       \
            acc[i][j] = G1_MFMA(afh[i], bfh[j], acc[i][j]);                 \
            acc[i][j] = G1_MFMA(afh[i], bfl[j], acc[i][j]);                 \
            acc[i][j] = G1_MFMA(afl[i], bfh[j], acc[i][j]);                 \
        }                                                                   \
    __builtin_amdgcn_s_setprio(0);                                          \
    asm volatile("s_waitcnt lgkmcnt(0)" ::: "memory");                      \
    __builtin_amdgcn_s_barrier();                                           \
    if ((t) + 2 < 32) G1_STAGE(AhB, AlB, BhB, BlB, ((t) + 2) * 32);         \
    __builtin_amdgcn_s_setprio(1);                                          \
    _Pragma("unroll")                                                       \
    for (int i = 2; i < 4; i++)                                             \
        _Pragma("unroll")                                                   \
        for (int j = 0; j < 4; j++) {                                       \
            acc[i][j] = G1_MFMA(afh[i], bfh[j], acc[i][j]);                 \
            acc[i][j] = G1_MFMA(afh[i], bfl[j], acc[i][j]);                 \
            acc[i][j] = G1_MFMA(afl[i], bfh[j], acc[i][j]);                 \
        }                                                                   \
    __builtin_amdgcn_s_setprio(0);                                          \
    if ((t) + 2 < 32)      asm volatile("s_waitcnt vmcnt(6)" ::: "memory"); \
    else if ((t) + 1 < 32) asm volatile("s_waitcnt vmcnt(0)" ::: "memory"); \
    __builtin_amdgcn_s_barrier();                                           \
} while (0)

__global__ __launch_bounds__(512, 2)
void gemm1_k(const u16* __restrict__ Ahg, const u16* __restrict__ Alg,
             const u16* __restrict__ Bhg, const u16* __restrict__ Blg,
             float* __restrict__ C) {
    // Two buffers as SEPARATE objects so the LDS-DMA waitcnt pass can
    // disambiguate: DMA into buf1 never forces a wait before ds_read of buf0.
    __shared__ u16 Ah0[128 * 32], Al0[128 * 32], Bh0[256 * 32], Bl0[256 * 32];
    __shared__ u16 Ah1[128 * 32], Al1[128 * 32], Bh1[256 * 32], Bl1[256 * 32];

    const int tid  = threadIdx.x;
    const int wave = tid >> 6, lane = tid & 63;
    const int wr = wave >> 2, wc = wave & 3;
    const int quad = lane >> 4, r16 = lane & 15;
    const int m0 = blockIdx.y * 128, n0 = blockIdx.x * 256;

    f32x4 zero = {0.f, 0.f, 0.f, 0.f};
    f32x4 acc[4][4];
#pragma unroll
    for (int i = 0; i < 4; i++)
#pragma unroll
        for (int j = 0; j < 4; j++) acc[i][j] = zero;

    // staging: thread t covers row t>>2, chunk t&3 (swizzled source column)
    const int arow = tid >> 2, achk = tid & 3;
    const int ascol = (achk ^ ((arow >> 1) & 3)) * 8;
    const u16* a_h = Ahg + (size_t)(m0 + arow) * H_ + ascol;
    const u16* a_l = Alg + (size_t)(m0 + arow) * H_ + ascol;
    const int brow0 = arow,        bscol0 = (achk ^ ((brow0 >> 1) & 3)) * 8;
    const int brow1 = 128 + arow,  bscol1 = (achk ^ ((brow1 >> 1) & 3)) * 8;
    const u16* b_h0 = Bhg + (size_t)(n0 + brow0) * H_ + bscol0;
    const u16* b_h1 = Bhg + (size_t)(n0 + brow1) * H_ + bscol1;
    const u16* b_l0 = Blg + (size_t)(n0 + brow0) * H_ + bscol0;
    const u16* b_l1 = Blg + (size_t)(n0 + brow1) * H_ + bscol1;
    const int tid16 = tid * 16;
    const int aswz = (r16 >> 1) & 3;

    // fragment LDS element offsets (same for both buffers)
    int aoff[4], boff[4];
#pragma unroll
    for (int i = 0; i < 4; i++) {
        aoff[i] = (wr * 64 + i * 16 + r16) * 32 + ((quad ^ aswz) * 8);
        boff[i] = (wc * 64 + i * 16 + r16) * 32 + ((quad ^ aswz) * 8);
    }

    // Prologue: stage tiles 0 and 1; wait only for tile 0 (vmcnt(6)).
    G1_STAGE(Ah0, Al0, Bh0, Bl0, 0);
    G1_STAGE(Ah1, Al1, Bh1, Bl1, 32);
    asm volatile("s_waitcnt vmcnt(6)" ::: "memory");
    __builtin_amdgcn_s_barrier();

    for (int t = 0; t < 32; t += 2) {
        G1_ITER(Ah0, Al0, Bh0, Bl0, t);
        G1_ITER(Ah1, Al1, Bh1, Bl1, t + 1);
    }

    // C/D layout: row = quad*4 + reg, col = lane&15
#pragma unroll
    for (int i = 0; i < 4; i++) {
        int gm = m0 + wr * 64 + i * 16 + quad * 4;
#pragma unroll
        for (int j = 0; j < 4; j++) {
            int gn = n0 + wc * 64 + j * 16 + r16;
            if (gn < DP1) {
#pragma unroll
                for (int reg = 0; reg < 4; reg++)
                    C[(size_t)(gm + reg) * DP1 + gn] = acc[i][j][reg];
            }
        }
    }
}

// ---------- fused softmax + sparse gather epilogue (aligned vector I/O) ----------
// One block per (b,l) row, 1024 threads. sim rows are misaligned by (row&3)
// floats (10001 % 4 == 1): a0 head elements are handled scalar so that all
// f32x4 accesses at rowp + a0 + 4k are 16B-aligned.
// concept[row] = p[D_]*desc[row] + sum_{d: e_d > 1e-7*Z} p_d * vocab[d].
// Dropped mass <= 1e-3 worst case; typically ~e^-16 (logits ~ N(0,32^2)).
__global__ __launch_bounds__(1024)
void softmax_gather_k(float* __restrict__ sim, const float* __restrict__ vocab,
                      const float* __restrict__ desc, float* __restrict__ out) {
    __shared__ float red[16];
    __shared__ float wslot;
    __shared__ int   cnt;
    __shared__ int   cidx[CANDS];
    __shared__ float cp[CANDS];
    const int tid = threadIdx.x;
    const int row = blockIdx.x;
    float* rowp = sim + (size_t)row * DP1;
    if (tid == 0) cnt = 0;

    const int a0 = (4 - (row & 3)) & 3;          // head elems for 16B alignment
    const int b0 = a0 + tid * 4;
    const int b1 = a0 + 4096 + tid * 4;
    const int b2 = a0 + 8192 + tid * 4;

    float vh = (tid < a0) ? rowp[tid] : -3.4e38f;   // head (<=3 elems, threads 0..2)
    f32x4 v0 = *(const f32x4*)(rowp + b0);          // aligned
    f32x4 v1 = *(const f32x4*)(rowp + b1);          // aligned
    f32x4 v2;
    if (b2 + 3 <= D_) {
        v2 = *(const f32x4*)(rowp + b2);            // aligned
    } else {
#pragma unroll
        for (int e = 0; e < 4; e++)
            v2[e] = (b2 + e <= D_) ? rowp[b2 + e] : -3.4e38f;
    }

    float mx = vh;
#pragma unroll
    for (int e = 0; e < 4; e++) mx = fmaxf(mx, fmaxf(v0[e], fmaxf(v1[e], v2[e])));
#pragma unroll
    for (int off = 32; off; off >>= 1) mx = fmaxf(mx, __shfl_down(mx, off, 64));
    if ((tid & 63) == 0) red[tid >> 6] = mx;
    __syncthreads();
#pragma unroll
    for (int w = 0; w < 16; w++) mx = fmaxf(mx, red[w]);

    float s0 = 0.f;
    vh = __expf(vh - mx); s0 += vh;                 // exp(-huge)=0 for non-head
#pragma unroll
    for (int e = 0; e < 4; e++) {
        v0[e] = __expf(v0[e] - mx); s0 += v0[e];
        v1[e] = __expf(v1[e] - mx); s0 += v1[e];
        v2[e] = __expf(v2[e] - mx); s0 += v2[e];    // exp(-huge)=0 for pad
    }
#pragma unroll
    for (int off = 32; off; off >>= 1) s0 += __shfl_down(s0, off, 64);
    __syncthreads();                                // red[] reuse hazard
    if ((tid & 63) == 0) red[tid >> 6] = s0;
    __syncthreads();
    float sum = 0.f;
#pragma unroll
    for (int w = 0; w < 16; w++) sum += red[w];
    const float inv = 1.f / sum;
    const float thr = sum * 1e-7f;

    // write normalized probs + collect candidates (concept slots d < D_)
    if (tid < a0) {                                 // head
        float p = vh * inv;
        rowp[tid] = p;
        if (vh > thr) {
            int k = atomicAdd(&cnt, 1);
            if (k < CANDS) { cidx[k] = tid; cp[k] = p; }
        }
    }
    {
        f32x4 p0 = v0 * inv;
        *(f32x4*)(rowp + b0) = p0;                  // aligned
#pragma unroll
        for (int e = 0; e < 4; e++)
            if (v0[e] > thr) {
                int k = atomicAdd(&cnt, 1);
                if (k < CANDS) { cidx[k] = b0 + e; cp[k] = p0[e]; }
            }
        f32x4 p1 = v1 * inv;
        *(f32x4*)(rowp + b1) = p1;                  // aligned
#pragma unroll
        for (int e = 0; e < 4; e++)
            if (v1[e] > thr) {
                int k = atomicAdd(&cnt, 1);
                if (k < CANDS) { cidx[k] = b1 + e; cp[k] = p1[e]; }
            }
#pragma unroll
        for (int e = 0; e < 4; e++) {
            int idx = b2 + e;
            if (idx <= D_) {
                float p = v2[e] * inv;
                rowp[idx] = p;
                if (idx == D_) wslot = p;
                else if (v2[e] > thr) {
                    int k = atomicAdd(&cnt, 1);
                    if (k < CANDS) { cidx[k] = idx; cp[k] = p; }
                }
            }
        }
    }
    __syncthreads();

    // gather: thread t owns H-column t (wave reads 256B contiguous)
    const float w = wslot;
    float a = w * desc[(size_t)row * H_ + tid];
    if (cnt <= CANDS) {
        const int k = cnt;
        for (int c = 0; c < k; c++)
            a += cp[c] * vocab[(size_t)cidx[c] * H_ + tid];
    } else {
        // overflow fallback (pathological rows only): scan normalized probs
        const float pthr = thr * inv;
        for (int d = 0; d < D_; d++) {
            float p = rowp[d];
            if (p > pthr) a += p * vocab[(size_t)d * H_ + tid];
        }
    }
    out[(size_t)row * H_ + tid] = a;
}

// ---------- fallback (ws too small): exact fp32 logits, slow but correct ----------
__global__ __launch_bounds__(256)
void naive_logits_k(const float* __restrict__ vocab, const float* __restrict__ desc,
                    const float* __restrict__ defe, float* __restrict__ sim) {
    int d = blockIdx.x * 256 + threadIdx.x;
    if (d >= DP1) return;
    const float* vr = (d < D_) ? (vocab + (size_t)d * H_) : defe;
    const float* dr = desc + (size_t)blockIdx.y * H_;
    float s = 0.f;
    for (int h = 0; h < H_; h++) s = fmaf(dr[h], vr[h], s);
    sim[(size_t)blockIdx.y * DP1 + d] = s;
}

extern "C" void kernel_launch(void* const* d_in, const int* in_sizes, int n_in,
                              void* d_out, int out_size, void* d_ws, size_t ws_size,
                              hipStream_t stream) {
    (void)in_sizes; (void)n_in; (void)out_size;
    const float* vocab = (const float*)d_in[0];
    const float* desc  = (const float*)d_in[1];
    const float* defe  = (const float*)d_in[2];
    float* out = (float*)d_out;                          // concept: [4096][1024]
    float* sim = out + (size_t)BL * H_;                  // sim:     [4096][10001]

    // ws layout (bytes):
    //   desc_hi @ 0          (8,388,608)
    //   desc_lo @ 8,388,608  (8,388,608)
    //   fv_hi   @ 16,777,216 (20,971,520 = NPAD2*H_*2)
    //   fv_lo   @ 37,748,736 (20,971,520)          -> REQ1 = 58,720,256
    const size_t REQ1 = 58720256ull;
    char* ws = (char*)d_ws;

    if (ws_size >= REQ1) {
        u16* dhi = (u16*)(ws + 0);
        u16* dlo = (u16*)(ws + 8388608);
        u16* fhi = (u16*)(ws + 16777216);
        u16* flo = (u16*)(ws + 37748736);

        split_desc_k<<<2048, 256, 0, stream>>>(desc, dhi, dlo);
        split_fv_k<<<5120, 256, 0, stream>>>(vocab, defe, fhi, flo);
        gemm1_k<<<dim3(40, 32), 512, 0, stream>>>(dhi, dlo, fhi, flo, sim);
    } else {
        naive_logits_k<<<dim3(40, BL), 256, 0, stream>>>(vocab, desc, defe, sim);
    }
    softmax_gather_k<<<4096, 1024, 0, stream>>>(sim, vocab, desc, out);
}

// Round 9
// 503.056 us; speedup vs baseline: 1.0252x; 1.0252x over previous
//
#include <hip/hip_runtime.h>
#include <stdint.h>

#define D_    10000
#define DP1   10001
#define NPAD2 10240      // 40 * 256 (padded vocab rows for GEMM1, N-tile 256)
#define H_    1024
#define BL    4096       // B * L
#define CANDS 1024       // fused-fallback candidate capacity
#define GC    256        // per-row exported candidate capacity (typ. 2-6 used)

typedef float  f32x4  __attribute__((ext_vector_type(4)));
typedef __bf16 bf16x8 __attribute__((ext_vector_type(8)));
typedef unsigned short u16;
typedef u16    u16x8  __attribute__((ext_vector_type(8)));

// ---------- bf16 helpers (round-to-nearest-even) ----------
__device__ __forceinline__ u16 f2bf(float x) {
    union { float f; unsigned u; } v; v.f = x;
    unsigned r = v.u + 0x7FFFu + ((v.u >> 16) & 1u);
    return (u16)(r >> 16);
}
__device__ __forceinline__ float bf2f(u16 b) {
    union { float f; unsigned u; } v; v.u = ((unsigned)b) << 16;
    return v.f;
}

// async global -> LDS, 16B per lane (HW: wave-uniform base + lane*16)
#define GLOAD_LDS16(gsrc, ldst)                                             \
    __builtin_amdgcn_global_load_lds(                                       \
        (__attribute__((address_space(1))) void*)(void*)(gsrc),             \
        (__attribute__((address_space(3))) void*)(void*)(ldst), 16, 0, 0)

// History:
// R3: LDS chunk swizzle -> SQ_LDS_BANK_CONFLICT 2.07e7 -> 0.
// R6: 2-deep prefetch + counted vmcnt, (512,2), 96KB: 248-252us (PROVEN).
// R7: 256^2 tile + 4-phase: REGRESSED. Reverted.
// R8: sparse-gather epilogue replaced gemm2 pipeline: 692->648us.
// R9/R10: spill disasters. LESSON: WRITE_SIZE >> output = scratch spill.
// R11: consolidation: 517us.
// R12 (occupancy/vectorize) + R13 (16B alignment): BOTH NEUTRAL (~512-516).
//   Three failed micro-fixes on softmax_gather whose duration we have
//   NEVER observed (top-5 = all gemm1 ~250us). Attribution now suspect.
// R14 (this): ABLATION-BY-SPLIT: softmax_cand_k (pure streaming: softmax +
//   candidate-list export to ws) + gather_k (sparse fp32 gather from list).
//   Decision tree: total -> ~360us => fused kernel was self-serializing;
//   total flat => missing ~165us is outside these kernels (harness overhead)
//   and gemm1 is the only remaining target.

// ---------- prep: split fp32 -> bf16 hi + lo (8 elements/thread) ----------
__global__ __launch_bounds__(256)
void split_desc_k(const float* __restrict__ desc, u16* __restrict__ hi, u16* __restrict__ lo) {
    size_t i = ((size_t)blockIdx.x * 256 + threadIdx.x) * 8;   // exactly BL*H_
    f32x4 x0 = *(const f32x4*)(desc + i);
    f32x4 x1 = *(const f32x4*)(desc + i + 4);
    u16x8 h, l;
#pragma unroll
    for (int e = 0; e < 4; e++) {
        h[e] = f2bf(x0[e]); l[e] = f2bf(x0[e] - bf2f(h[e]));
        h[4 + e] = f2bf(x1[e]); l[4 + e] = f2bf(x1[e] - bf2f(h[4 + e]));
    }
    *(u16x8*)(hi + i) = h;
    *(u16x8*)(lo + i) = l;
}

__global__ __launch_bounds__(256)
void split_fv_k(const float* __restrict__ vocab, const float* __restrict__ defe,
                u16* __restrict__ hi, u16* __restrict__ lo) {
    size_t i = ((size_t)blockIdx.x * 256 + threadIdx.x) * 8;   // exactly NPAD2*H_
    int d = (int)(i >> 10);                                    // 8-chunk never crosses rows
    f32x4 x0 = {0.f, 0.f, 0.f, 0.f}, x1 = {0.f, 0.f, 0.f, 0.f};
    if (d < D_) {
        x0 = *(const f32x4*)(vocab + i);
        x1 = *(const f32x4*)(vocab + i + 4);
    } else if (d == D_) {
        int h = (int)(i & 1023);
        x0 = *(const f32x4*)(defe + h);
        x1 = *(const f32x4*)(defe + h + 4);
    }
    u16x8 h8, l8;
#pragma unroll
    for (int e = 0; e < 4; e++) {
        h8[e] = f2bf(x0[e]); l8[e] = f2bf(x0[e] - bf2f(h8[e]));
        h8[4 + e] = f2bf(x1[e]); l8[4 + e] = f2bf(x1[e] - bf2f(h8[4 + e]));
    }
    *(u16x8*)(hi + i) = h8;
    *(u16x8*)(lo + i) = l8;
}

// ---------- GEMM1: logits = desc @ full_vocab^T, bf16 hi/lo split (3 MFMAs) ----------
// Tile 128(M) x 256(N), BK=32, 512 threads (8 waves, wave grid 2x4, 64x64/wave).
// Double-buffered LDS (96 KB), 2-deep prefetch with counted vmcnt.  [R6 form]

#define G1_MFMA(a, b, c) __builtin_amdgcn_mfma_f32_16x16x32_bf16((a), (b), (c), 0, 0, 0)

#define G1_STAGE(AhB, AlB, BhB, BlB, kk) do {                               \
    GLOAD_LDS16(a_h  + (kk), (char*)(AhB) + tid16);                         \
    GLOAD_LDS16(a_l  + (kk), (char*)(AlB) + tid16);                         \
    GLOAD_LDS16(b_h0 + (kk), (char*)(BhB) + tid16);                         \
    GLOAD_LDS16(b_h1 + (kk), (char*)(BhB) + tid16 + 8192);                  \
    GLOAD_LDS16(b_l0 + (kk), (char*)(BlB) + tid16);                         \
    GLOAD_LDS16(b_l1 + (kk), (char*)(BlB) + tid16 + 8192);                  \
} while (0)

// One K-tile: phase 0 = {ds_read 16 frags, 24 MFMA (i=0,1), lgkmcnt(0), barrier}
//             phase 1 = {STAGE t+2 -> this buffer, 24 MFMA (i=2,3), vmcnt(6), barrier}
// vmcnt(6): tile t+1's 6 loads (oldest) complete; tile t+2's 6 stay in flight.
#define G1_ITER(AhB, AlB, BhB, BlB, t) do {                                 \
    bf16x8 afh[4], afl[4], bfh[4], bfl[4];                                  \
    _Pragma("unroll")                                                       \
    for (int i = 0; i < 4; i++) {                                           \
        afh[i] = *(const bf16x8*)&AhB[aoff[i]];                             \
        afl[i] = *(const bf16x8*)&AlB[aoff[i]];                             \
        bfh[i] = *(const bf16x8*)&BhB[boff[i]];                             \
        bfl[i] = *(const bf16x8*)&BlB[boff[i]];                             \
    }                                                                       \
    __builtin_amdgcn_s_setprio(1);                                          \
    _Pragma("unroll")                                                       \
    for (int i = 0; i < 2; i++)                                             \
        _Pragma("unroll")                                                   \
        for (int j = 0; j < 4; j++) {                                       \
            acc[i][j] = G1_MFMA(afh[i], bfh[j], acc[i][j]);                 \
            acc[i][j] = G1_MFMA(afh[i], bfl[j], acc[i][j]);                 \
            acc[i][j] = G1_MFMA(afl[i], bfh[j], acc[i][j]);                 \
        }                                                                   \
    __builtin_amdgcn_s_setprio(0);                                          \
    asm volatile("s_waitcnt lgkmcnt(0)" ::: "memory");                      \
    __builtin_amdgcn_s_barrier();                                           \
    if ((t) + 2 < 32) G1_STAGE(AhB, AlB, BhB, BlB, ((t) + 2) * 32);         \
    __builtin_amdgcn_s_setprio(1);                                          \
    _Pragma("unroll")                                                       \
    for (int i = 2; i < 4; i++)                                             \
        _Pragma("unroll")                                                   \
        for (int j = 0; j < 4; j++) {                                       \
            acc[i][j] = G1_MFMA(afh[i], bfh[j], acc[i][j]);                 \
            acc[i][j] = G1_MFMA(afh[i], bfl[j], acc[i][j]);                 \
            acc[i][j] = G1_MFMA(afl[i], bfh[j], acc[i][j]);                 \
        }                                                                   \
    __builtin_amdgcn_s_setprio(0);                                          \
    if ((t) + 2 < 32)      asm volatile("s_waitcnt vmcnt(6)" ::: "memory"); \
    else if ((t) + 1 < 32) asm volatile("s_waitcnt vmcnt(0)" ::: "memory"); \
    __builtin_amdgcn_s_barrier();                                           \
} while (0)

__global__ __launch_bounds__(512, 2)
void gemm1_k(const u16* __restrict__ Ahg, const u16* __restrict__ Alg,
             const u16* __restrict__ Bhg, const u16* __restrict__ Blg,
             float* __restrict__ C) {
    // Two buffers as SEPARATE objects so the LDS-DMA waitcnt pass can
    // disambiguate: DMA into buf1 never forces a wait before ds_read of buf0.
    __shared__ u16 Ah0[128 * 32], Al0[128 * 32], Bh0[256 * 32], Bl0[256 * 32];
    __shared__ u16 Ah1[128 * 32], Al1[128 * 32], Bh1[256 * 32], Bl1[256 * 32];

    const int tid  = threadIdx.x;
    const int wave = tid >> 6, lane = tid & 63;
    const int wr = wave >> 2, wc = wave & 3;
    const int quad = lane >> 4, r16 = lane & 15;
    const int m0 = blockIdx.y * 128, n0 = blockIdx.x * 256;

    f32x4 zero = {0.f, 0.f, 0.f, 0.f};
    f32x4 acc[4][4];
#pragma unroll
    for (int i = 0; i < 4; i++)
#pragma unroll
        for (int j = 0; j < 4; j++) acc[i][j] = zero;

    // staging: thread t covers row t>>2, chunk t&3 (swizzled source column)
    const int arow = tid >> 2, achk = tid & 3;
    const int ascol = (achk ^ ((arow >> 1) & 3)) * 8;
    const u16* a_h = Ahg + (size_t)(m0 + arow) * H_ + ascol;
    const u16* a_l = Alg + (size_t)(m0 + arow) * H_ + ascol;
    const int brow0 = arow,        bscol0 = (achk ^ ((brow0 >> 1) & 3)) * 8;
    const int brow1 = 128 + arow,  bscol1 = (achk ^ ((brow1 >> 1) & 3)) * 8;
    const u16* b_h0 = Bhg + (size_t)(n0 + brow0) * H_ + bscol0;
    const u16* b_h1 = Bhg + (size_t)(n0 + brow1) * H_ + bscol1;
    const u16* b_l0 = Blg + (size_t)(n0 + brow0) * H_ + bscol0;
    const u16* b_l1 = Blg + (size_t)(n0 + brow1) * H_ + bscol1;
    const int tid16 = tid * 16;
    const int aswz = (r16 >> 1) & 3;

    // fragment LDS element offsets (same for both buffers)
    int aoff[4], boff[4];
#pragma unroll
    for (int i = 0; i < 4; i++) {
        aoff[i] = (wr * 64 + i * 16 + r16) * 32 + ((quad ^ aswz) * 8);
        boff[i] = (wc * 64 + i * 16 + r16) * 32 + ((quad ^ aswz) * 8);
    }

    // Prologue: stage tiles 0 and 1; wait only for tile 0 (vmcnt(6)).
    G1_STAGE(Ah0, Al0, Bh0, Bl0, 0);
    G1_STAGE(Ah1, Al1, Bh1, Bl1, 32);
    asm volatile("s_waitcnt vmcnt(6)" ::: "memory");
    __builtin_amdgcn_s_barrier();

    for (int t = 0; t < 32; t += 2) {
        G1_ITER(Ah0, Al0, Bh0, Bl0, t);
        G1_ITER(Ah1, Al1, Bh1, Bl1, t + 1);
    }

    // C/D layout: row = quad*4 + reg, col = lane&15
#pragma unroll
    for (int i = 0; i < 4; i++) {
        int gm = m0 + wr * 64 + i * 16 + quad * 4;
#pragma unroll
        for (int j = 0; j < 4; j++) {
            int gn = n0 + wc * 64 + j * 16 + r16;
            if (gn < DP1) {
#pragma unroll
                for (int reg = 0; reg < 4; reg++)
                    C[(size_t)(gm + reg) * DP1 + gn] = acc[i][j][reg];
            }
        }
    }
}

// ---------- softmax + candidate export (pure streaming) ----------
// One block per (b,l) row, 1024 threads. Aligned vector I/O (head fix-up a0).
// Writes normalized probs to sim; exports {cnt, wslot, cidx[], cp[]} to ws.
// Candidate criterion: e > sum*1e-7  <=>  p > 1e-7. Dropped mass <= 1e-3
// worst case; typically ~e^-16 (logits ~ N(0,32^2), near-one-hot).
__global__ __launch_bounds__(1024)
void softmax_cand_k(float* __restrict__ sim, int* __restrict__ gcnt,
                    float* __restrict__ gws, int* __restrict__ gcidx,
                    float* __restrict__ gcp) {
    __shared__ float red[16];
    __shared__ int   cnt;
    __shared__ int   cidx[GC];
    __shared__ float cp[GC];
    const int tid = threadIdx.x;
    const int row = blockIdx.x;
    float* rowp = sim + (size_t)row * DP1;
    if (tid == 0) cnt = 0;

    const int a0 = (4 - (row & 3)) & 3;          // head elems for 16B alignment
    const int b0 = a0 + tid * 4;
    const int b1 = a0 + 4096 + tid * 4;
    const int b2 = a0 + 8192 + tid * 4;

    float vh = (tid < a0) ? rowp[tid] : -3.4e38f;
    f32x4 v0 = *(const f32x4*)(rowp + b0);
    f32x4 v1 = *(const f32x4*)(rowp + b1);
    f32x4 v2;
    if (b2 + 3 <= D_) {
        v2 = *(const f32x4*)(rowp + b2);
    } else {
#pragma unroll
        for (int e = 0; e < 4; e++)
            v2[e] = (b2 + e <= D_) ? rowp[b2 + e] : -3.4e38f;
    }

    float mx = vh;
#pragma unroll
    for (int e = 0; e < 4; e++) mx = fmaxf(mx, fmaxf(v0[e], fmaxf(v1[e], v2[e])));
#pragma unroll
    for (int off = 32; off; off >>= 1) mx = fmaxf(mx, __shfl_down(mx, off, 64));
    if ((tid & 63) == 0) red[tid >> 6] = mx;
    __syncthreads();
#pragma unroll
    for (int w = 0; w < 16; w++) mx = fmaxf(mx, red[w]);

    float s0 = 0.f;
    vh = __expf(vh - mx); s0 += vh;
#pragma unroll
    for (int e = 0; e < 4; e++) {
        v0[e] = __expf(v0[e] - mx); s0 += v0[e];
        v1[e] = __expf(v1[e] - mx); s0 += v1[e];
        v2[e] = __expf(v2[e] - mx); s0 += v2[e];    // exp(-huge)=0 for pad
    }
#pragma unroll
    for (int off = 32; off; off >>= 1) s0 += __shfl_down(s0, off, 64);
    __syncthreads();                                // red[] reuse hazard
    if ((tid & 63) == 0) red[tid >> 6] = s0;
    __syncthreads();
    float sum = 0.f;
#pragma unroll
    for (int w = 0; w < 16; w++) sum += red[w];
    const float inv = 1.f / sum;
    const float thr = sum * 1e-7f;

    // write normalized probs + collect candidates (concept slots d < D_)
    if (tid < a0) {
        float p = vh * inv;
        rowp[tid] = p;
        if (vh > thr) {
            int k = atomicAdd(&cnt, 1);
            if (k < GC) { cidx[k] = tid; cp[k] = p; }
        }
    }
    {
        f32x4 p0 = v0 * inv;
        *(f32x4*)(rowp + b0) = p0;
#pragma unroll
        for (int e = 0; e < 4; e++)
            if (v0[e] > thr) {
                int k = atomicAdd(&cnt, 1);
                if (k < GC) { cidx[k] = b0 + e; cp[k] = p0[e]; }
            }
        f32x4 p1 = v1 * inv;
        *(f32x4*)(rowp + b1) = p1;
#pragma unroll
        for (int e = 0; e < 4; e++)
            if (v1[e] > thr) {
                int k = atomicAdd(&cnt, 1);
                if (k < GC) { cidx[k] = b1 + e; cp[k] = p1[e]; }
            }
#pragma unroll
        for (int e = 0; e < 4; e++) {
            int idx = b2 + e;
            if (idx <= D_) {
                float p = v2[e] * inv;
                rowp[idx] = p;
                if (idx == D_) gws[row] = p;            // default-slot weight
                else if (v2[e] > thr) {
                    int k = atomicAdd(&cnt, 1);
                    if (k < GC) { cidx[k] = idx; cp[k] = p; }
                }
            }
        }
    }
    __syncthreads();

    const int k = cnt < GC ? cnt : GC;
    if (tid < k) {
        gcidx[(size_t)row * GC + tid] = cidx[tid];
        gcp[(size_t)row * GC + tid]   = cp[tid];
    }
    if (tid == 0) gcnt[row] = cnt;
}

// ---------- sparse gather: out[row] = wslot*desc[row] + sum_c p_c*vocab[d_c] ----------
__global__ __launch_bounds__(256)
void gather_k(const float* __restrict__ sim, const int* __restrict__ gcnt,
              const float* __restrict__ gws, const int* __restrict__ gcidx,
              const float* __restrict__ gcp,
              const float* __restrict__ vocab, const float* __restrict__ desc,
              float* __restrict__ out) {
    const int tid = threadIdx.x;
    const int row = blockIdx.x;
    const int cnt = gcnt[row];
    f32x4 a = gws[row] * ((const f32x4*)(desc + (size_t)row * H_))[tid];
    if (cnt <= GC) {
        for (int c = 0; c < cnt; c++) {
            int d   = gcidx[(size_t)row * GC + c];
            float p = gcp[(size_t)row * GC + c];
            a += p * ((const f32x4*)(vocab + (size_t)d * H_))[tid];
        }
    } else {
        // overflow fallback (never on this data): full scan of normalized probs
        const float* rowp = sim + (size_t)row * DP1;
        for (int d = 0; d < D_; d++) {
            float p = rowp[d];
            if (p > 1e-7f) a += p * ((const f32x4*)(vocab + (size_t)d * H_))[tid];
        }
    }
    ((f32x4*)(out + (size_t)row * H_))[tid] = a;
}

// ---------- fused fallback (small ws): softmax + gather in one (R13 form) ----------
__global__ __launch_bounds__(1024)
void softmax_gather_k(float* __restrict__ sim, const float* __restrict__ vocab,
                      const float* __restrict__ desc, float* __restrict__ out) {
    __shared__ float red[16];
    __shared__ float wslot;
    __shared__ int   cnt;
    __shared__ int   cidx[CANDS];
    __shared__ float cp[CANDS];
    const int tid = threadIdx.x;
    const int row = blockIdx.x;
    float* rowp = sim + (size_t)row * DP1;
    if (tid == 0) cnt = 0;

    const int a0 = (4 - (row & 3)) & 3;
    const int b0 = a0 + tid * 4;
    const int b1 = a0 + 4096 + tid * 4;
    const int b2 = a0 + 8192 + tid * 4;

    float vh = (tid < a0) ? rowp[tid] : -3.4e38f;
    f32x4 v0 = *(const f32x4*)(rowp + b0);
    f32x4 v1 = *(const f32x4*)(rowp + b1);
    f32x4 v2;
    if (b2 + 3 <= D_) {
        v2 = *(const f32x4*)(rowp + b2);
    } else {
#pragma unroll
        for (int e = 0; e < 4; e++)
            v2[e] = (b2 + e <= D_) ? rowp[b2 + e] : -3.4e38f;
    }

    float mx = vh;
#pragma unroll
    for (int e = 0; e < 4; e++) mx = fmaxf(mx, fmaxf(v0[e], fmaxf(v1[e], v2[e])));
#pragma unroll
    for (int off = 32; off; off >>= 1) mx = fmaxf(mx, __shfl_down(mx, off, 64));
    if ((tid & 63) == 0) red[tid >> 6] = mx;
    __syncthreads();
#pragma unroll
    for (int w = 0; w < 16; w++) mx = fmaxf(mx, red[w]);

    float s0 = 0.f;
    vh = __expf(vh - mx); s0 += vh;
#pragma unroll
    for (int e = 0; e < 4; e++) {
        v0[e] = __expf(v0[e] - mx); s0 += v0[e];
        v1[e] = __expf(v1[e] - mx); s0 += v1[e];
        v2[e] = __expf(v2[e] - mx); s0 += v2[e];
    }
#pragma unroll
    for (int off = 32; off; off >>= 1) s0 += __shfl_down(s0, off, 64);
    __syncthreads();
    if ((tid & 63) == 0) red[tid >> 6] = s0;
    __syncthreads();
    float sum = 0.f;
#pragma unroll
    for (int w = 0; w < 16; w++) sum += red[w];
    const float inv = 1.f / sum;
    const float thr = sum * 1e-7f;

    if (tid < a0) {
        float p = vh * inv;
        rowp[tid] = p;
        if (vh > thr) {
            int k = atomicAdd(&cnt, 1);
            if (k < CANDS) { cidx[k] = tid; cp[k] = p; }
        }
    }
    {
        f32x4 p0 = v0 * inv;
        *(f32x4*)(rowp + b0) = p0;
#pragma unroll
        for (int e = 0; e < 4; e++)
            if (v0[e] > thr) {
                int k = atomicAdd(&cnt, 1);
                if (k < CANDS) { cidx[k] = b0 + e; cp[k] = p0[e]; }
            }
        f32x4 p1 = v1 * inv;
        *(f32x4*)(rowp + b1) = p1;
#pragma unroll
        for (int e = 0; e < 4; e++)
            if (v1[e] > thr) {
                int k = atomicAdd(&cnt, 1);
                if (k < CANDS) { cidx[k] = b1 + e; cp[k] = p1[e]; }
            }
#pragma unroll
        for (int e = 0; e < 4; e++) {
            int idx = b2 + e;
            if (idx <= D_) {
                float p = v2[e] * inv;
                rowp[idx] = p;
                if (idx == D_) wslot = p;
                else if (v2[e] > thr) {
                    int k = atomicAdd(&cnt, 1);
                    if (k < CANDS) { cidx[k] = idx; cp[k] = p; }
                }
            }
        }
    }
    __syncthreads();

    const float w = wslot;
    float a = w * desc[(size_t)row * H_ + tid];
    if (cnt <= CANDS) {
        const int k = cnt;
        for (int c = 0; c < k; c++)
            a += cp[c] * vocab[(size_t)cidx[c] * H_ + tid];
    } else {
        const float pthr = thr * inv;
        for (int d = 0; d < D_; d++) {
            float p = rowp[d];
            if (p > pthr) a += p * vocab[(size_t)d * H_ + tid];
        }
    }
    out[(size_t)row * H_ + tid] = a;
}

// ---------- fallback (ws too small): exact fp32 logits, slow but correct ----------
__global__ __launch_bounds__(256)
void naive_logits_k(const float* __restrict__ vocab, const float* __restrict__ desc,
                    const float* __restrict__ defe, float* __restrict__ sim) {
    int d = blockIdx.x * 256 + threadIdx.x;
    if (d >= DP1) return;
    const float* vr = (d < D_) ? (vocab + (size_t)d * H_) : defe;
    const float* dr = desc + (size_t)blockIdx.y * H_;
    float s = 0.f;
    for (int h = 0; h < H_; h++) s = fmaf(dr[h], vr[h], s);
    sim[(size_t)blockIdx.y * DP1 + d] = s;
}

extern "C" void kernel_launch(void* const* d_in, const int* in_sizes, int n_in,
                              void* d_out, int out_size, void* d_ws, size_t ws_size,
                              hipStream_t stream) {
    (void)in_sizes; (void)n_in; (void)out_size;
    const float* vocab = (const float*)d_in[0];
    const float* desc  = (const float*)d_in[1];
    const float* defe  = (const float*)d_in[2];
    float* out = (float*)d_out;                          // concept: [4096][1024]
    float* sim = out + (size_t)BL * H_;                  // sim:     [4096][10001]

    // ws layout (bytes):
    //   desc_hi @ 0          (8,388,608)
    //   desc_lo @ 8,388,608  (8,388,608)
    //   fv_hi   @ 16,777,216 (20,971,520 = NPAD2*H_*2)
    //   fv_lo   @ 37,748,736 (20,971,520)          -> REQ1 = 58,720,256
    // After gemm1 the split arrays are dead; candidate lists reuse ws+0:
    //   gcnt  @ 0          (16,384)
    //   gws   @ 16,384     (16,384)
    //   gcidx @ 32,768     (4,194,304 = BL*GC*4)
    //   gcp   @ 4,227,072  (4,194,304)            -> 8,421,376 total
    const size_t REQ1 = 58720256ull;
    char* ws = (char*)d_ws;

    if (ws_size >= REQ1) {
        u16* dhi = (u16*)(ws + 0);
        u16* dlo = (u16*)(ws + 8388608);
        u16* fhi = (u16*)(ws + 16777216);
        u16* flo = (u16*)(ws + 37748736);

        split_desc_k<<<2048, 256, 0, stream>>>(desc, dhi, dlo);
        split_fv_k<<<5120, 256, 0, stream>>>(vocab, defe, fhi, flo);
        gemm1_k<<<dim3(40, 32), 512, 0, stream>>>(dhi, dlo, fhi, flo, sim);

        int*   gcnt  = (int*)(ws + 0);
        float* gws   = (float*)(ws + 16384);
        int*   gcidx = (int*)(ws + 32768);
        float* gcp   = (float*)(ws + 4227072);
        softmax_cand_k<<<4096, 1024, 0, stream>>>(sim, gcnt, gws, gcidx, gcp);
        gather_k<<<4096, 256, 0, stream>>>(sim, gcnt, gws, gcidx, gcp, vocab, desc, out);
    } else {
        naive_logits_k<<<dim3(40, BL), 256, 0, stream>>>(vocab, desc, defe, sim);
        softmax_gather_k<<<4096, 1024, 0, stream>>>(sim, vocab, desc, out);
    }
}

// Round 10
// 389.201 us; speedup vs baseline: 1.3251x; 1.2925x over previous
//
#include <hip/hip_runtime.h>
#include <stdint.h>

#define D_    10000
#define DP1   10001
#define NPAD2 10240      // 40 * 256 (padded vocab rows for GEMM1, N-tile 256)
#define H_    1024
#define BL    4096       // B * L
#define CANDS 1024       // fused-fallback candidate capacity
#define GC    512        // per-row exported candidate capacity (typ. 1-6 used)

typedef float  f32x4  __attribute__((ext_vector_type(4)));
typedef __bf16 bf16x8 __attribute__((ext_vector_type(8)));
typedef unsigned short u16;
typedef u16    u16x8  __attribute__((ext_vector_type(8)));

// ---------- bf16 helpers (round-to-nearest-even) ----------
__device__ __forceinline__ u16 f2bf(float x) {
    union { float f; unsigned u; } v; v.f = x;
    unsigned r = v.u + 0x7FFFu + ((v.u >> 16) & 1u);
    return (u16)(r >> 16);
}

// async global -> LDS, 16B per lane (HW: wave-uniform base + lane*16)
#define GLOAD_LDS16(gsrc, ldst)                                             \
    __builtin_amdgcn_global_load_lds(                                       \
        (__attribute__((address_space(1))) void*)(void*)(gsrc),             \
        (__attribute__((address_space(3))) void*)(void*)(ldst), 16, 0, 0)

// History:
// R3: LDS chunk swizzle -> SQ_LDS_BANK_CONFLICT 0. R6: counted-vmcnt 2-phase
//   (PROVEN 248-252us for hi/lo). R7 4-phase 256^2: regressed. R8: sparse-
//   gather replaced gemm2: 648us. R9/R10: spill disasters (WRITE_SIZE >>
//   output = spill). R11: 517us. R12/R13 micro-fixes: neutral.
// R14: split softmax/gather: ~neutral (503us) -> "softmax slow" FALSIFIED.
//   Timestamp gap: pipeline ~418us; non-gemm1 ~165us vs ~95us floor. Tail
//   is near-roofline. CORRECTED ARITHMETIC (R9 was 4x off): MFMA floor =
//   19.4cy/SIMD per 16x16x32 -> gemm1 floor 124us; 253us = 49% matrix-pipe
//   = the 2-phase structure's documented ceiling. Path: shrink the work.
// R15 (this): bf16-only gemm1 (1 MFMA not 3; floor 41us; 48KB LDS -> more
//   TLP). Logit error ~0.06 only matters for p>1e-8 rows -> candidates
//   (typ 1-6/row) recomputed EXACTLY in fp32 inside gather_k (per-wave dot
//   products), exact max/Z/p scattered into sim. Non-candidates keep bf16-
//   based p (error < 1e-7). Candidate p gets MORE accurate than hi/lo.

// ---------- prep: fp32 -> bf16 (8 elements/thread) ----------
__global__ __launch_bounds__(256)
void split_desc_k(const float* __restrict__ desc, u16* __restrict__ hi) {
    size_t i = ((size_t)blockIdx.x * 256 + threadIdx.x) * 8;   // exactly BL*H_
    f32x4 x0 = *(const f32x4*)(desc + i);
    f32x4 x1 = *(const f32x4*)(desc + i + 4);
    u16x8 h;
#pragma unroll
    for (int e = 0; e < 4; e++) { h[e] = f2bf(x0[e]); h[4 + e] = f2bf(x1[e]); }
    *(u16x8*)(hi + i) = h;
}

__global__ __launch_bounds__(256)
void split_fv_k(const float* __restrict__ vocab, const float* __restrict__ defe,
                u16* __restrict__ hi) {
    size_t i = ((size_t)blockIdx.x * 256 + threadIdx.x) * 8;   // exactly NPAD2*H_
    int d = (int)(i >> 10);                                    // 8-chunk never crosses rows
    f32x4 x0 = {0.f, 0.f, 0.f, 0.f}, x1 = {0.f, 0.f, 0.f, 0.f};
    if (d < D_) {
        x0 = *(const f32x4*)(vocab + i);
        x1 = *(const f32x4*)(vocab + i + 4);
    } else if (d == D_) {
        int h = (int)(i & 1023);
        x0 = *(const f32x4*)(defe + h);
        x1 = *(const f32x4*)(defe + h + 4);
    }
    u16x8 h8;
#pragma unroll
    for (int e = 0; e < 4; e++) { h8[e] = f2bf(x0[e]); h8[4 + e] = f2bf(x1[e]); }
    *(u16x8*)(hi + i) = h8;
}

// ---------- GEMM1 (bf16-only): logits ~ desc @ full_vocab^T ----------
// Tile 128(M) x 256(N), BK=32, 512 threads (8 waves, 2x4, 64x64/wave).
// LDS 48KB double-buffered; 2-deep prefetch, counted vmcnt(3). [R6 shape]

#define G1_MFMA(a, b, c) __builtin_amdgcn_mfma_f32_16x16x32_bf16((a), (b), (c), 0, 0, 0)

#define G1_STAGE(AhB, BhB, kk) do {                                         \
    GLOAD_LDS16(a_h  + (kk), (char*)(AhB) + tid16);                         \
    GLOAD_LDS16(b_h0 + (kk), (char*)(BhB) + tid16);                         \
    GLOAD_LDS16(b_h1 + (kk), (char*)(BhB) + tid16 + 8192);                  \
} while (0)

// phase 0 = {ds_read 8 frags, 8 MFMA (i=0,1), lgkmcnt(0), barrier}
// phase 1 = {STAGE t+2 -> this buffer, 8 MFMA (i=2,3), vmcnt(3), barrier}
// vmcnt(3): tile t+1's 3 loads complete; tile t+2's 3 stay in flight.
#define G1_ITER(AhB, BhB, t) do {                                           \
    bf16x8 afh[4], bfh[4];                                                  \
    _Pragma("unroll")                                                       \
    for (int i = 0; i < 4; i++) {                                           \
        afh[i] = *(const bf16x8*)&AhB[aoff[i]];                             \
        bfh[i] = *(const bf16x8*)&BhB[boff[i]];                             \
    }                                                                       \
    __builtin_amdgcn_s_setprio(1);                                          \
    _Pragma("unroll")                                                       \
    for (int i = 0; i < 2; i++)                                             \
        _Pragma("unroll")                                                   \
        for (int j = 0; j < 4; j++)                                         \
            acc[i][j] = G1_MFMA(afh[i], bfh[j], acc[i][j]);                 \
    __builtin_amdgcn_s_setprio(0);                                          \
    asm volatile("s_waitcnt lgkmcnt(0)" ::: "memory");                      \
    __builtin_amdgcn_s_barrier();                                           \
    if ((t) + 2 < 32) G1_STAGE(AhB, BhB, ((t) + 2) * 32);                   \
    __builtin_amdgcn_s_setprio(1);                                          \
    _Pragma("unroll")                                                       \
    for (int i = 2; i < 4; i++)                                             \
        _Pragma("unroll")                                                   \
        for (int j = 0; j < 4; j++)                                         \
            acc[i][j] = G1_MFMA(afh[i], bfh[j], acc[i][j]);                 \
    __builtin_amdgcn_s_setprio(0);                                          \
    if ((t) + 2 < 32)      asm volatile("s_waitcnt vmcnt(3)" ::: "memory"); \
    else if ((t) + 1 < 32) asm volatile("s_waitcnt vmcnt(0)" ::: "memory"); \
    __builtin_amdgcn_s_barrier();                                           \
} while (0)

__global__ __launch_bounds__(512, 2)
void gemm1_k(const u16* __restrict__ Ahg, const u16* __restrict__ Bhg,
             float* __restrict__ C) {
    __shared__ u16 Ah0[128 * 32], Bh0[256 * 32];
    __shared__ u16 Ah1[128 * 32], Bh1[256 * 32];

    const int tid  = threadIdx.x;
    const int wave = tid >> 6, lane = tid & 63;
    const int wr = wave >> 2, wc = wave & 3;
    const int quad = lane >> 4, r16 = lane & 15;
    const int m0 = blockIdx.y * 128, n0 = blockIdx.x * 256;

    f32x4 zero = {0.f, 0.f, 0.f, 0.f};
    f32x4 acc[4][4];
#pragma unroll
    for (int i = 0; i < 4; i++)
#pragma unroll
        for (int j = 0; j < 4; j++) acc[i][j] = zero;

    // staging: thread t covers row t>>2, chunk t&3 (swizzled source column)
    const int arow = tid >> 2, achk = tid & 3;
    const int ascol = (achk ^ ((arow >> 1) & 3)) * 8;
    const u16* a_h = Ahg + (size_t)(m0 + arow) * H_ + ascol;
    const int brow0 = arow,        bscol0 = (achk ^ ((brow0 >> 1) & 3)) * 8;
    const int brow1 = 128 + arow,  bscol1 = (achk ^ ((brow1 >> 1) & 3)) * 8;
    const u16* b_h0 = Bhg + (size_t)(n0 + brow0) * H_ + bscol0;
    const u16* b_h1 = Bhg + (size_t)(n0 + brow1) * H_ + bscol1;
    const int tid16 = tid * 16;
    const int aswz = (r16 >> 1) & 3;

    int aoff[4], boff[4];
#pragma unroll
    for (int i = 0; i < 4; i++) {
        aoff[i] = (wr * 64 + i * 16 + r16) * 32 + ((quad ^ aswz) * 8);
        boff[i] = (wc * 64 + i * 16 + r16) * 32 + ((quad ^ aswz) * 8);
    }

    // Prologue: stage tiles 0 and 1; wait only for tile 0 (vmcnt(3)).
    G1_STAGE(Ah0, Bh0, 0);
    G1_STAGE(Ah1, Bh1, 32);
    asm volatile("s_waitcnt vmcnt(3)" ::: "memory");
    __builtin_amdgcn_s_barrier();

    for (int t = 0; t < 32; t += 2) {
        G1_ITER(Ah0, Bh0, t);
        G1_ITER(Ah1, Bh1, t + 1);
    }

    // C/D layout: row = quad*4 + reg, col = lane&15
#pragma unroll
    for (int i = 0; i < 4; i++) {
        int gm = m0 + wr * 64 + i * 16 + quad * 4;
#pragma unroll
        for (int j = 0; j < 4; j++) {
            int gn = n0 + wc * 64 + j * 16 + r16;
            if (gn < DP1) {
#pragma unroll
                for (int reg = 0; reg < 4; reg++)
                    C[(size_t)(gm + reg) * DP1 + gn] = acc[i][j][reg];
            }
        }
    }
}

// ---------- softmax + candidate export (bf16 logits, pure streaming) ----------
// One block per (b,l) row, 1024 threads. Aligned vector I/O (head fix-up a0).
// Candidate criterion: e > sum*1e-8 (margin for bf16 logit error ~0.06).
// Non-candidate true p < ~4e-8 -> bf16-based p is within 1e-7 of reference.
__global__ __launch_bounds__(1024)
void softmax_cand_k(float* __restrict__ sim, int* __restrict__ gcnt,
                    int* __restrict__ gcidx) {
    __shared__ float red[16];
    __shared__ int   cnt;
    __shared__ int   cidx[GC];
    const int tid = threadIdx.x;
    const int row = blockIdx.x;
    float* rowp = sim + (size_t)row * DP1;
    if (tid == 0) cnt = 0;

    const int a0 = (4 - (row & 3)) & 3;          // head elems for 16B alignment
    const int b0 = a0 + tid * 4;
    const int b1 = a0 + 4096 + tid * 4;
    const int b2 = a0 + 8192 + tid * 4;

    float vh = (tid < a0) ? rowp[tid] : -3.4e38f;
    f32x4 v0 = *(const f32x4*)(rowp + b0);
    f32x4 v1 = *(const f32x4*)(rowp + b1);
    f32x4 v2;
    if (b2 + 3 <= D_) {
        v2 = *(const f32x4*)(rowp + b2);
    } else {
#pragma unroll
        for (int e = 0; e < 4; e++)
            v2[e] = (b2 + e <= D_) ? rowp[b2 + e] : -3.4e38f;
    }

    float mx = vh;
#pragma unroll
    for (int e = 0; e < 4; e++) mx = fmaxf(mx, fmaxf(v0[e], fmaxf(v1[e], v2[e])));
#pragma unroll
    for (int off = 32; off; off >>= 1) mx = fmaxf(mx, __shfl_down(mx, off, 64));
    if ((tid & 63) == 0) red[tid >> 6] = mx;
    __syncthreads();
#pragma unroll
    for (int w = 0; w < 16; w++) mx = fmaxf(mx, red[w]);

    float s0 = 0.f;
    vh = __expf(vh - mx); s0 += vh;
#pragma unroll
    for (int e = 0; e < 4; e++) {
        v0[e] = __expf(v0[e] - mx); s0 += v0[e];
        v1[e] = __expf(v1[e] - mx); s0 += v1[e];
        v2[e] = __expf(v2[e] - mx); s0 += v2[e];    // exp(-huge)=0 for pad
    }
#pragma unroll
    for (int off = 32; off; off >>= 1) s0 += __shfl_down(s0, off, 64);
    __syncthreads();                                // red[] reuse hazard
    if ((tid & 63) == 0) red[tid >> 6] = s0;
    __syncthreads();
    float sum = 0.f;
#pragma unroll
    for (int w = 0; w < 16; w++) sum += red[w];
    const float inv = 1.f / sum;
    const float thr = sum * 1e-8f;

    // write bf16-based probs + collect candidate indices (d < D_)
    if (tid < a0) {
        float p = vh * inv;
        rowp[tid] = p;
        if (vh > thr) {
            int k = atomicAdd(&cnt, 1);
            if (k < GC) cidx[k] = tid;
        }
    }
    {
        f32x4 p0 = v0 * inv;
        *(f32x4*)(rowp + b0) = p0;
#pragma unroll
        for (int e = 0; e < 4; e++)
            if (v0[e] > thr) {
                int k = atomicAdd(&cnt, 1);
                if (k < GC) cidx[k] = b0 + e;
            }
        f32x4 p1 = v1 * inv;
        *(f32x4*)(rowp + b1) = p1;
#pragma unroll
        for (int e = 0; e < 4; e++)
            if (v1[e] > thr) {
                int k = atomicAdd(&cnt, 1);
                if (k < GC) cidx[k] = b1 + e;
            }
#pragma unroll
        for (int e = 0; e < 4; e++) {
            int idx = b2 + e;
            if (idx <= D_) {
                float p = v2[e] * inv;
                rowp[idx] = p;                       // D_ overwritten exactly in gather
                if (idx < D_ && v2[e] > thr) {
                    int k = atomicAdd(&cnt, 1);
                    if (k < GC) cidx[k] = idx;
                }
            }
        }
    }
    __syncthreads();

    const int k = cnt < GC ? cnt : GC;
    if (tid < k) gcidx[(size_t)row * GC + tid] = cidx[tid];
    if (tid == 0) gcnt[row] = cnt;
}

// ---------- exact sparse finish: fp32 logits for candidates + default ----------
// Per row: recompute l_c = desc[row].vocab[d_c] (and l_def = desc[row].defe)
// exactly in fp32 (wave-parallel dots), rebuild max/Z/p from exact values,
// scatter exact p into sim, emit out = p_def*desc + sum p_c*vocab[d_c].
__global__ __launch_bounds__(256)
void gather_k(float* __restrict__ sim, const int* __restrict__ gcnt,
              const int* __restrict__ gcidx,
              const float* __restrict__ vocab, const float* __restrict__ defe,
              const float* __restrict__ desc, float* __restrict__ out) {
    __shared__ float lex[GC + 1];
    __shared__ float psh[GC + 1];
    const int tid = threadIdx.x;
    const int row = blockIdx.x;
    const int cnt0 = gcnt[row];
    const int cnt = cnt0 < GC ? cnt0 : GC;
    const float* drow = desc + (size_t)row * H_;
    const int lane = tid & 63, wv = tid >> 6;
    const int* crow = gcidx + (size_t)row * GC;

    // exact logits: wave wv handles candidates c = wv, wv+4, ...; c==cnt => default
    for (int c = wv; c <= cnt; c += 4) {
        const float* vrow = (c == cnt) ? defe : (vocab + (size_t)crow[c] * H_);
        float s = 0.f;
#pragma unroll
        for (int q = 0; q < 4; q++) {
            f32x4 dv = *(const f32x4*)(drow + (q * 64 + lane) * 4);
            f32x4 vv = *(const f32x4*)(vrow + (q * 64 + lane) * 4);
            s += dv[0] * vv[0] + dv[1] * vv[1] + dv[2] * vv[2] + dv[3] * vv[3];
        }
#pragma unroll
        for (int off = 32; off; off >>= 1) s += __shfl_down(s, off, 64);
        if (lane == 0) lex[c] = s;
    }
    __syncthreads();

    // exact max / Z over cnt+1 entries (tiny; redundant per-thread from LDS)
    float m = -3.4e38f;
    for (int c = 0; c <= cnt; c++) m = fmaxf(m, lex[c]);
    float Z = 0.f;
    for (int c = 0; c <= cnt; c++) Z += __expf(lex[c] - m);
    const float invZ = 1.f / Z;
    for (int i = tid; i <= cnt; i += 256) psh[i] = __expf(lex[i] - m) * invZ;
    __syncthreads();

    // scatter exact p into sim (candidates + default slot)
    float* rowp = sim + (size_t)row * DP1;
    for (int c = tid; c < cnt; c += 256) rowp[crow[c]] = psh[c];
    if (tid == 0) rowp[D_] = psh[cnt];

    // output: thread t owns 4 consecutive H-columns
    f32x4 a = psh[cnt] * ((const f32x4*)drow)[tid];
    if (cnt0 <= GC) {
        for (int c = 0; c < cnt; c++)
            a += psh[c] * ((const f32x4*)(vocab + (size_t)crow[c] * H_))[tid];
    } else {
        // overflow fallback (never on this data): full scan of bf16-based probs
        for (int d = 0; d < D_; d++) {
            float p = rowp[d];
            if (p > 1e-8f) a += p * ((const f32x4*)(vocab + (size_t)d * H_))[tid];
        }
    }
    ((f32x4*)(out + (size_t)row * H_))[tid] = a;
}

// ---------- fallback (ws too small): exact fp32 logits + fused epilogue ----------
__global__ __launch_bounds__(256)
void naive_logits_k(const float* __restrict__ vocab, const float* __restrict__ desc,
                    const float* __restrict__ defe, float* __restrict__ sim) {
    int d = blockIdx.x * 256 + threadIdx.x;
    if (d >= DP1) return;
    const float* vr = (d < D_) ? (vocab + (size_t)d * H_) : defe;
    const float* dr = desc + (size_t)blockIdx.y * H_;
    float s = 0.f;
    for (int h = 0; h < H_; h++) s = fmaf(dr[h], vr[h], s);
    sim[(size_t)blockIdx.y * DP1 + d] = s;
}

__global__ __launch_bounds__(1024)
void softmax_gather_k(float* __restrict__ sim, const float* __restrict__ vocab,
                      const float* __restrict__ desc, float* __restrict__ out) {
    __shared__ float red[16];
    __shared__ float wslot;
    __shared__ int   cnt;
    __shared__ int   cidx[CANDS];
    __shared__ float cp[CANDS];
    const int tid = threadIdx.x;
    const int row = blockIdx.x;
    float* rowp = sim + (size_t)row * DP1;
    if (tid == 0) cnt = 0;

    const int a0 = (4 - (row & 3)) & 3;
    const int b0 = a0 + tid * 4;
    const int b1 = a0 + 4096 + tid * 4;
    const int b2 = a0 + 8192 + tid * 4;

    float vh = (tid < a0) ? rowp[tid] : -3.4e38f;
    f32x4 v0 = *(const f32x4*)(rowp + b0);
    f32x4 v1 = *(const f32x4*)(rowp + b1);
    f32x4 v2;
    if (b2 + 3 <= D_) {
        v2 = *(const f32x4*)(rowp + b2);
    } else {
#pragma unroll
        for (int e = 0; e < 4; e++)
            v2[e] = (b2 + e <= D_) ? rowp[b2 + e] : -3.4e38f;
    }

    float mx = vh;
#pragma unroll
    for (int e = 0; e < 4; e++) mx = fmaxf(mx, fmaxf(v0[e], fmaxf(v1[e], v2[e])));
#pragma unroll
    for (int off = 32; off; off >>= 1) mx = fmaxf(mx, __shfl_down(mx, off, 64));
    if ((tid & 63) == 0) red[tid >> 6] = mx;
    __syncthreads();
#pragma unroll
    for (int w = 0; w < 16; w++) mx = fmaxf(mx, red[w]);

    float s0 = 0.f;
    vh = __expf(vh - mx); s0 += vh;
#pragma unroll
    for (int e = 0; e < 4; e++) {
        v0[e] = __expf(v0[e] - mx); s0 += v0[e];
        v1[e] = __expf(v1[e] - mx); s0 += v1[e];
        v2[e] = __expf(v2[e] - mx); s0 += v2[e];
    }
#pragma unroll
    for (int off = 32; off; off >>= 1) s0 += __shfl_down(s0, off, 64);
    __syncthreads();
    if ((tid & 63) == 0) red[tid >> 6] = s0;
    __syncthreads();
    float sum = 0.f;
#pragma unroll
    for (int w = 0; w < 16; w++) sum += red[w];
    const float inv = 1.f / sum;
    const float thr = sum * 1e-7f;

    if (tid < a0) {
        float p = vh * inv;
        rowp[tid] = p;
        if (vh > thr) {
            int k = atomicAdd(&cnt, 1);
            if (k < CANDS) { cidx[k] = tid; cp[k] = p; }
        }
    }
    {
        f32x4 p0 = v0 * inv;
        *(f32x4*)(rowp + b0) = p0;
#pragma unroll
        for (int e = 0; e < 4; e++)
            if (v0[e] > thr) {
                int k = atomicAdd(&cnt, 1);
                if (k < CANDS) { cidx[k] = b0 + e; cp[k] = p0[e]; }
            }
        f32x4 p1 = v1 * inv;
        *(f32x4*)(rowp + b1) = p1;
#pragma unroll
        for (int e = 0; e < 4; e++)
            if (v1[e] > thr) {
                int k = atomicAdd(&cnt, 1);
                if (k < CANDS) { cidx[k] = b1 + e; cp[k] = p1[e]; }
            }
#pragma unroll
        for (int e = 0; e < 4; e++) {
            int idx = b2 + e;
            if (idx <= D_) {
                float p = v2[e] * inv;
                rowp[idx] = p;
                if (idx == D_) wslot = p;
                else if (v2[e] > thr) {
                    int k = atomicAdd(&cnt, 1);
                    if (k < CANDS) { cidx[k] = idx; cp[k] = p; }
                }
            }
        }
    }
    __syncthreads();

    const float w = wslot;
    float a = w * desc[(size_t)row * H_ + tid];
    if (cnt <= CANDS) {
        const int k = cnt;
        for (int c = 0; c < k; c++)
            a += cp[c] * vocab[(size_t)cidx[c] * H_ + tid];
    } else {
        const float pthr = thr * inv;
        for (int d = 0; d < D_; d++) {
            float p = rowp[d];
            if (p > pthr) a += p * vocab[(size_t)d * H_ + tid];
        }
    }
    out[(size_t)row * H_ + tid] = a;
}

extern "C" void kernel_launch(void* const* d_in, const int* in_sizes, int n_in,
                              void* d_out, int out_size, void* d_ws, size_t ws_size,
                              hipStream_t stream) {
    (void)in_sizes; (void)n_in; (void)out_size;
    const float* vocab = (const float*)d_in[0];
    const float* desc  = (const float*)d_in[1];
    const float* defe  = (const float*)d_in[2];
    float* out = (float*)d_out;                          // concept: [4096][1024]
    float* sim = out + (size_t)BL * H_;                  // sim:     [4096][10001]

    // ws layout (bytes):
    //   desc_bf @ 0          (8,388,608)
    //   fv_bf   @ 8,388,608  (20,971,520 = NPAD2*H_*2) -> REQ1 = 29,360,128
    // After gemm1 the split arrays are dead; candidate lists reuse ws+0:
    //   gcnt  @ 0       (16,384)
    //   gcidx @ 32,768  (8,388,608 = BL*GC*4)
    const size_t REQ1 = 29360128ull;
    char* ws = (char*)d_ws;

    if (ws_size >= REQ1) {
        u16* dhi = (u16*)(ws + 0);
        u16* fhi = (u16*)(ws + 8388608);

        split_desc_k<<<2048, 256, 0, stream>>>(desc, dhi);
        split_fv_k<<<5120, 256, 0, stream>>>(vocab, defe, fhi);
        gemm1_k<<<dim3(40, 32), 512, 0, stream>>>(dhi, fhi, sim);

        int* gcnt  = (int*)(ws + 0);
        int* gcidx = (int*)(ws + 32768);
        softmax_cand_k<<<4096, 1024, 0, stream>>>(sim, gcnt, gcidx);
        gather_k<<<4096, 256, 0, stream>>>(sim, gcnt, gcidx, vocab, defe, desc, out);
    } else {
        naive_logits_k<<<dim3(40, BL), 256, 0, stream>>>(vocab, desc, defe, sim);
        softmax_gather_k<<<4096, 1024, 0, stream>>>(sim, vocab, desc, out);
    }
}